// Round 1
// baseline (92.619 us; speedup 1.0000x reference)
//
#include <hip/hip_runtime.h>

#define NB 256
#define NV 1024
#define NF_IN 16
#define NA 8
#define NP 16
#define NOUT 32

__global__ __launch_bounds__(512, 2) void garnet_fused(
    const float* __restrict__ data,      // (B,V,F)
    const int*   __restrict__ num_vertex,// (B,1)
    const float* __restrict__ W_flr,     // (F,P)
    const float* __restrict__ b_flr,     // (P)
    const float* __restrict__ W_s,       // (F,A)
    const float* __restrict__ b_s,       // (A)
    const float* __restrict__ W_out,     // (A*P, NOUT)
    const float* __restrict__ b_out,     // (NOUT)
    float* __restrict__ out)             // (B,V,NOUT)
{
    __shared__ float ew_s[NV * NA];        // 32 KiB, ew[v][a]
    __shared__ float part[8][NA * 17];     // per-wave partials (tmp[16]+sumew)
    __shared__ float fin[NA * 17];
    __shared__ float agg_s[NA * NP];
    __shared__ float M_s[NA * NOUT];

    const int t = threadIdx.x;             // 0..511
    const int b = blockIdx.x;
    const int nv = num_vertex[b];
    const float* __restrict__ db = data + (size_t)b * (NV * NF_IN);

    // ---------------- Phase 1: ew + tmp[a][f] accumulation ----------------
    const int a  = t & 7;                  // this thread's aggregator
    const int vg = t >> 3;                 // vertex group 0..63

    float wcol[NF_IN];
    #pragma unroll
    for (int f = 0; f < NF_IN; ++f) wcol[f] = W_s[f * NA + a];
    const float bs = b_s[a];

    float tmp[NF_IN];
    #pragma unroll
    for (int f = 0; f < NF_IN; ++f) tmp[f] = 0.0f;
    float sumew = 0.0f;

    for (int i = 0; i < 16; ++i) {
        const int v = vg + 64 * i;
        const float4* dp = (const float4*)(db + v * NF_IN);
        float4 q0 = dp[0], q1 = dp[1], q2 = dp[2], q3 = dp[3];
        float d[NF_IN] = {q0.x,q0.y,q0.z,q0.w, q1.x,q1.y,q1.z,q1.w,
                          q2.x,q2.y,q2.z,q2.w, q3.x,q3.y,q3.z,q3.w};
        float dist = bs;
        #pragma unroll
        for (int f = 0; f < NF_IN; ++f) dist += d[f] * wcol[f];
        // exp(dist * -ln2) == exp2(-dist); fold vertex mask into ew
        float e = (v < nv) ? exp2f(-dist) : 0.0f;
        ew_s[v * NA + a] = e;
        sumew += e;
        #pragma unroll
        for (int f = 0; f < NF_IN; ++f) tmp[f] += e * d[f];
    }

    // wave-level reduce across the 8 lanes sharing `a` (lane bits 3..5)
    #pragma unroll
    for (int m = 8; m <= 32; m <<= 1) {
        #pragma unroll
        for (int f = 0; f < NF_IN; ++f) tmp[f] += __shfl_xor(tmp[f], m, 64);
        sumew += __shfl_xor(sumew, m, 64);
    }
    const int lane = t & 63, w = t >> 6;
    if (lane < 8) {                        // lane == a for lanes 0..7
        #pragma unroll
        for (int f = 0; f < NF_IN; ++f) part[w][lane * 17 + f] = tmp[f];
        part[w][lane * 17 + 16] = sumew;
    }
    __syncthreads();

    // cross-wave combine: 136 values
    if (t < NA * 17) {
        float s = 0.0f;
        #pragma unroll
        for (int w2 = 0; w2 < 8; ++w2) s += part[w2][t];
        fin[t] = s;
    }
    __syncthreads();

    // agg[a][p] = (tmp[a][:] . W_flr[:,p] + sumew[a]*b_flr[p]) / V
    if (t < NA * NP) {
        const int aa = t >> 4, p = t & 15;
        float s = 0.0f;
        #pragma unroll
        for (int f = 0; f < NF_IN; ++f) s += fin[aa * 17 + f] * W_flr[f * NP + p];
        s += fin[aa * 17 + 16] * b_flr[p];
        agg_s[aa * NP + p] = s * (1.0f / (float)NV);
    }
    __syncthreads();

    // M[a][n] = sum_p agg[a][p] * W_out[(a*P+p)*NOUT + n]
    if (t < NA * NOUT) {
        const int aa = t >> 5, n = t & 31;
        float s = 0.0f;
        #pragma unroll
        for (int p = 0; p < NP; ++p)
            s += agg_s[aa * NP + p] * W_out[(aa * NP + p) * NOUT + n];
        M_s[aa * NOUT + n] = s;
    }
    __syncthreads();

    // ---------------- Phase 2: out[v][n] = mask*(sum_a ew[v][a]*M[a][n] + b_out[n])
    const int n4 = (t & 7) * 4;            // n-quad
    const int vb = t >> 3;                 // vertex base 0..63
    float4 Mr[NA];
    #pragma unroll
    for (int aa = 0; aa < NA; ++aa) Mr[aa] = *(const float4*)&M_s[aa * NOUT + n4];
    const float4 bo = *(const float4*)&b_out[n4];
    float* __restrict__ ob = out + (size_t)b * (NV * NOUT);

    for (int i = 0; i < 16; ++i) {
        const int v = vb + 64 * i;
        float4 e0 = *(const float4*)&ew_s[v * NA];
        float4 e1 = *(const float4*)&ew_s[v * NA + 4];
        float4 acc = make_float4(0.f, 0.f, 0.f, 0.f);
        const float ev[NA] = {e0.x, e0.y, e0.z, e0.w, e1.x, e1.y, e1.z, e1.w};
        #pragma unroll
        for (int aa = 0; aa < NA; ++aa) {
            acc.x += ev[aa] * Mr[aa].x;
            acc.y += ev[aa] * Mr[aa].y;
            acc.z += ev[aa] * Mr[aa].z;
            acc.w += ev[aa] * Mr[aa].w;
        }
        float4 o;
        if (v < nv) {
            o.x = acc.x + bo.x; o.y = acc.y + bo.y;
            o.z = acc.z + bo.z; o.w = acc.w + bo.w;
        } else {
            o = make_float4(0.f, 0.f, 0.f, 0.f);
        }
        *(float4*)&ob[v * NOUT + n4] = o;
    }
}

extern "C" void kernel_launch(void* const* d_in, const int* in_sizes, int n_in,
                              void* d_out, int out_size, void* d_ws, size_t ws_size,
                              hipStream_t stream) {
    const float* data       = (const float*)d_in[0];
    const int*   num_vertex = (const int*)  d_in[1];
    const float* W_flr      = (const float*)d_in[2];
    const float* b_flr      = (const float*)d_in[3];
    const float* W_s        = (const float*)d_in[4];
    const float* b_s        = (const float*)d_in[5];
    const float* W_out      = (const float*)d_in[6];
    const float* b_out      = (const float*)d_in[7];
    float* out = (float*)d_out;

    hipLaunchKernelGGL(garnet_fused, dim3(NB), dim3(512), 0, stream,
                       data, num_vertex, W_flr, b_flr, W_s, b_s, W_out, b_out, out);
}